// Round 1
// baseline (1412.312 us; speedup 1.0000x reference)
//
#include <hip/hip_runtime.h>
#include <math.h>

#define CIN 256
#define KCB 4096
#define NPOS 16384  // 16*32*32

// output offsets (in floats)
#define OFF_QUANT 0
#define OFF_IDX   4194304    // 16*256*32*32
#define OFF_LOGIT 4210688    // OFF_IDX + 16*32*32
#define OFF_V     71319552   // OFF_LOGIT + 16*32*32*4096

// ---------------------------------------------------------------------------
// K1: kmat[k][c] = sum_j codebook[k][j]*wk[c][j];  v[k][c] likewise with wv.
// One block = 16 codebook rows, 256 threads (thread = output channel c).
// ---------------------------------------------------------------------------
__global__ __launch_bounds__(256) void kv_kernel(
    const float* __restrict__ cb, const float* __restrict__ wk,
    const float* __restrict__ wv, float* __restrict__ kmat,
    float* __restrict__ vout) {
  __shared__ float cbs[16][CIN];
  const int t = threadIdx.x;
  const int k0 = blockIdx.x * 16;
#pragma unroll
  for (int i = 0; i < 16; ++i)
    cbs[i][t] = cb[(size_t)(k0 + i) * CIN + t];
  __syncthreads();
  float acck[16], accv[16];
#pragma unroll
  for (int r = 0; r < 16; ++r) { acck[r] = 0.f; accv[r] = 0.f; }
  const float* wkr = wk + (size_t)t * CIN;
  const float* wvr = wv + (size_t)t * CIN;
  for (int j = 0; j < CIN; ++j) {
    const float a = wkr[j];
    const float b = wvr[j];
#pragma unroll
    for (int r = 0; r < 16; ++r) {
      const float c = cbs[r][j];
      acck[r] = fmaf(c, a, acck[r]);
      accv[r] = fmaf(c, b, accv[r]);
    }
  }
#pragma unroll
  for (int r = 0; r < 16; ++r) {
    kmat[(size_t)(k0 + r) * CIN + t] = acck[r];
    vout[(size_t)(k0 + r) * CIN + t] = accv[r];
  }
}

// ---------------------------------------------------------------------------
// K2: q[p][d] = sum_c latent[n][c][h][w] * wq[d][c], p = n*1024 + h*32 + w.
// One block = 16 consecutive positions (same n), 256 threads (thread = d).
// ---------------------------------------------------------------------------
__global__ __launch_bounds__(256) void q_kernel(
    const float* __restrict__ latent, const float* __restrict__ wq,
    float* __restrict__ q) {
  __shared__ float lat[16][CIN];  // [hw offset][channel]
  const int t = threadIdx.x;
  const int p0 = blockIdx.x * 16;
  const int n = p0 >> 10, hw0 = p0 & 1023;
  const float* lbase = latent + (size_t)n * (CIN * 1024) + (size_t)t * 1024 + hw0;
#pragma unroll
  for (int i4 = 0; i4 < 4; ++i4) {
    float4 v4 = *(const float4*)(lbase + i4 * 4);
    lat[i4 * 4 + 0][t] = v4.x;
    lat[i4 * 4 + 1][t] = v4.y;
    lat[i4 * 4 + 2][t] = v4.z;
    lat[i4 * 4 + 3][t] = v4.w;
  }
  __syncthreads();
  float acc[16];
#pragma unroll
  for (int r = 0; r < 16; ++r) acc[r] = 0.f;
  const float* wqr = wq + (size_t)t * CIN;
  for (int j = 0; j < CIN; ++j) {
    const float w = wqr[j];
#pragma unroll
    for (int r = 0; r < 16; ++r) acc[r] = fmaf(lat[r][j], w, acc[r]);
  }
#pragma unroll
  for (int r = 0; r < 16; ++r)
    q[(size_t)(p0 + r) * CIN + t] = acc[r];
}

// ---------------------------------------------------------------------------
// K3: logit[m][k] = dot(q[m], kmat[k]) / 16.   M=16384, N=4096, K=256.
// 64x64 tile per 256-thread block, 4x4 micro-tile per thread.
// ---------------------------------------------------------------------------
__global__ __launch_bounds__(256) void logit_kernel(
    const float* __restrict__ q, const float* __restrict__ kmat,
    float* __restrict__ logit) {
  __shared__ float As[16][68];  // [kk][row-in-tile], padded stride 68
  __shared__ float Bs[16][68];
  const int t = threadIdx.x;
  const int tx = t & 15, ty = t >> 4;
  const int n0 = blockIdx.x * 64;
  const int m0 = blockIdx.y * 64;
  const int lrow = t >> 2, lc4 = t & 3;

  float acc[4][4];
#pragma unroll
  for (int i = 0; i < 4; ++i)
#pragma unroll
    for (int j = 0; j < 4; ++j) acc[i][j] = 0.f;

  for (int k0 = 0; k0 < CIN; k0 += 16) {
    float4 a4 = *(const float4*)&q[(size_t)(m0 + lrow) * CIN + k0 + lc4 * 4];
    float4 b4 = *(const float4*)&kmat[(size_t)(n0 + lrow) * CIN + k0 + lc4 * 4];
    As[lc4 * 4 + 0][lrow] = a4.x;
    As[lc4 * 4 + 1][lrow] = a4.y;
    As[lc4 * 4 + 2][lrow] = a4.z;
    As[lc4 * 4 + 3][lrow] = a4.w;
    Bs[lc4 * 4 + 0][lrow] = b4.x;
    Bs[lc4 * 4 + 1][lrow] = b4.y;
    Bs[lc4 * 4 + 2][lrow] = b4.z;
    Bs[lc4 * 4 + 3][lrow] = b4.w;
    __syncthreads();
#pragma unroll
    for (int kk = 0; kk < 16; ++kk) {
      float4 av = *(const float4*)&As[kk][ty * 4];
      float4 bv = *(const float4*)&Bs[kk][tx * 4];
      acc[0][0] = fmaf(av.x, bv.x, acc[0][0]);
      acc[0][1] = fmaf(av.x, bv.y, acc[0][1]);
      acc[0][2] = fmaf(av.x, bv.z, acc[0][2]);
      acc[0][3] = fmaf(av.x, bv.w, acc[0][3]);
      acc[1][0] = fmaf(av.y, bv.x, acc[1][0]);
      acc[1][1] = fmaf(av.y, bv.y, acc[1][1]);
      acc[1][2] = fmaf(av.y, bv.z, acc[1][2]);
      acc[1][3] = fmaf(av.y, bv.w, acc[1][3]);
      acc[2][0] = fmaf(av.z, bv.x, acc[2][0]);
      acc[2][1] = fmaf(av.z, bv.y, acc[2][1]);
      acc[2][2] = fmaf(av.z, bv.z, acc[2][2]);
      acc[2][3] = fmaf(av.z, bv.w, acc[2][3]);
      acc[3][0] = fmaf(av.w, bv.x, acc[3][0]);
      acc[3][1] = fmaf(av.w, bv.y, acc[3][1]);
      acc[3][2] = fmaf(av.w, bv.z, acc[3][2]);
      acc[3][3] = fmaf(av.w, bv.w, acc[3][3]);
    }
    __syncthreads();
  }
  const float sc = 0.0625f;  // 1/sqrt(256)
#pragma unroll
  for (int i = 0; i < 4; ++i) {
    float4 o = make_float4(acc[i][0] * sc, acc[i][1] * sc, acc[i][2] * sc,
                           acc[i][3] * sc);
    *(float4*)&logit[(size_t)(m0 + ty * 4 + i) * KCB + n0 + tx * 4] = o;
  }
}

// ---------------------------------------------------------------------------
// K4: per-position softmax over 4096 logits + argmax, soft_v = soft @ v,
//     quantized = (v[idx] - soft_v) + soft_v (exact reference op order),
//     idx output as float(idx & 255)  (uint8 wrap).
// One block = 16 positions, 256 threads.
// ---------------------------------------------------------------------------
__global__ __launch_bounds__(256) void attn_kernel(
    const float* __restrict__ logit, const float* __restrict__ vout,
    float* __restrict__ outq, float* __restrict__ outidx) {
  __shared__ float vt[64 * 256];  // 64KB v tile; reused as qsh in epilogue
  __shared__ float pt[64][20];    // [kk][row], padded
  __shared__ float rowm[16], rowiz[16];
  __shared__ int rowidx[16];
  const int t = threadIdx.x;
  const int p0 = blockIdx.x * 16;
  const int n = p0 >> 10, hw0 = p0 & 1023;

  // ---- phase 1: max / argmax / sumexp per row (16 lanes per row) ----
  {
    const int r = t >> 4, l16 = t & 15;
    const float* lrow = logit + (size_t)(p0 + r) * KCB;
    float m = -3.402823466e38f;
    int mi = 0;
    for (int kk = 0; kk < 256; ++kk) {
      const int k = l16 + (kk << 4);
      const float x = lrow[k];
      if (x > m) { m = x; mi = k; }
    }
#pragma unroll
    for (int mask = 1; mask < 16; mask <<= 1) {
      const float om = __shfl_xor(m, mask, 64);
      const int oi = __shfl_xor(mi, mask, 64);
      if (om > m || (om == m && oi < mi)) { m = om; mi = oi; }
    }
    float s = 0.f;
    for (int kk = 0; kk < 256; ++kk) {
      const int k = l16 + (kk << 4);
      s += __expf(lrow[k] - m);
    }
#pragma unroll
    for (int mask = 1; mask < 16; mask <<= 1) s += __shfl_xor(s, mask, 64);
    if (l16 == 0) {
      rowm[r] = m;
      rowiz[r] = 1.f / s;
      rowidx[r] = mi;
    }
  }
  __syncthreads();

  // ---- phase 2: soft_v = soft @ v, k-tiled by 64 ----
  const int cg = t & 63, rg = t >> 6;  // thread owns cols cg*4..+3, rows rg*4..+3
  float acc[4][4];
#pragma unroll
  for (int i = 0; i < 4; ++i)
#pragma unroll
    for (int j = 0; j < 4; ++j) acc[i][j] = 0.f;

  for (int k0 = 0; k0 < KCB; k0 += 64) {
#pragma unroll
    for (int i = 0; i < 16; ++i) {
      const int f = t + i * 256;
      const int row = f >> 6, c4 = f & 63;
      *(float4*)&vt[row * 256 + c4 * 4] =
          *(const float4*)&vout[(size_t)(k0 + row) * CIN + c4 * 4];
    }
#pragma unroll
    for (int i = 0; i < 4; ++i) {
      const int f = t + i * 256;
      const int r = f >> 6, kk = f & 63;
      const float x = logit[(size_t)(p0 + r) * KCB + k0 + kk];
      pt[kk][r] = __expf(x - rowm[r]) * rowiz[r];
    }
    __syncthreads();
#pragma unroll
    for (int kk = 0; kk < 64; ++kk) {
      const float4 vv = *(const float4*)&vt[kk * 256 + cg * 4];
      const float4 pp = *(const float4*)&pt[kk][rg * 4];
      acc[0][0] = fmaf(pp.x, vv.x, acc[0][0]);
      acc[0][1] = fmaf(pp.x, vv.y, acc[0][1]);
      acc[0][2] = fmaf(pp.x, vv.z, acc[0][2]);
      acc[0][3] = fmaf(pp.x, vv.w, acc[0][3]);
      acc[1][0] = fmaf(pp.y, vv.x, acc[1][0]);
      acc[1][1] = fmaf(pp.y, vv.y, acc[1][1]);
      acc[1][2] = fmaf(pp.y, vv.z, acc[1][2]);
      acc[1][3] = fmaf(pp.y, vv.w, acc[1][3]);
      acc[2][0] = fmaf(pp.z, vv.x, acc[2][0]);
      acc[2][1] = fmaf(pp.z, vv.y, acc[2][1]);
      acc[2][2] = fmaf(pp.z, vv.z, acc[2][2]);
      acc[2][3] = fmaf(pp.z, vv.w, acc[2][3]);
      acc[3][0] = fmaf(pp.w, vv.x, acc[3][0]);
      acc[3][1] = fmaf(pp.w, vv.y, acc[3][1]);
      acc[3][2] = fmaf(pp.w, vv.z, acc[3][2]);
      acc[3][3] = fmaf(pp.w, vv.w, acc[3][3]);
    }
    __syncthreads();
  }

  // ---- epilogue: stage soft_v into LDS (reuse vt), combine with hard_v ----
  float* qsh = vt;  // [256][20] layout, 5120 floats <= 16384
#pragma unroll
  for (int ri = 0; ri < 4; ++ri)
#pragma unroll
    for (int ci = 0; ci < 4; ++ci)
      qsh[(cg * 4 + ci) * 20 + rg * 4 + ri] = acc[ri][ci];
  __syncthreads();

  float res[16];
#pragma unroll
  for (int r = 0; r < 16; ++r) {
    const float soft = qsh[t * 20 + r];
    const float hard = vout[(size_t)rowidx[r] * CIN + t];
    res[r] = (hard - soft) + soft;  // replicate reference op order exactly
  }
  float* ob = outq + (size_t)n * (CIN * 1024) + (size_t)t * 1024 + hw0;
#pragma unroll
  for (int i4 = 0; i4 < 4; ++i4)
    *(float4*)&ob[i4 * 4] = make_float4(res[i4 * 4 + 0], res[i4 * 4 + 1],
                                        res[i4 * 4 + 2], res[i4 * 4 + 3]);
  if (t < 16) outidx[p0 + t] = (float)(rowidx[t] & 255);
}

// ---------------------------------------------------------------------------
extern "C" void kernel_launch(void* const* d_in, const int* in_sizes, int n_in,
                              void* d_out, int out_size, void* d_ws,
                              size_t ws_size, hipStream_t stream) {
  const float* latent = (const float*)d_in[0];
  // d_in[1] = temperature (unused in deterministic path)
  const float* codebook = (const float*)d_in[2];
  const float* wq = (const float*)d_in[3];
  const float* wk = (const float*)d_in[4];
  const float* wv = (const float*)d_in[5];

  float* out = (float*)d_out;
  float* outq = out + OFF_QUANT;
  float* outidx = out + OFF_IDX;
  float* outlogit = out + OFF_LOGIT;
  float* outv = out + OFF_V;

  float* q_ws = (float*)d_ws;                 // 16384*256 floats = 16 MB
  float* kmat_ws = q_ws + (size_t)NPOS * CIN; // 4096*256 floats = 4 MB

  kv_kernel<<<KCB / 16, 256, 0, stream>>>(codebook, wk, wv, kmat_ws, outv);
  q_kernel<<<NPOS / 16, 256, 0, stream>>>(latent, wq, q_ws);
  logit_kernel<<<dim3(KCB / 64, NPOS / 64), 256, 0, stream>>>(q_ws, kmat_ws,
                                                              outlogit);
  attn_kernel<<<NPOS / 16, 256, 0, stream>>>(outlogit, outv, outq, outidx);
}

// Round 2
// 558.017 us; speedup vs baseline: 2.5309x; 2.5309x over previous
//
#include <hip/hip_runtime.h>
#include <math.h>

#define CIN 256
#define KCB 4096
#define NPOS 16384  // 16*32*32

// output offsets (in floats)
#define OFF_QUANT 0
#define OFF_IDX   4194304    // 16*256*32*32
#define OFF_LOGIT 4210688    // OFF_IDX + 16*32*32
#define OFF_V     71319552   // OFF_LOGIT + 16*32*32*4096

// ---------------------------------------------------------------------------
// K1: kmat[k][c] = sum_j codebook[k][j]*wk[c][j];  v[k][c] likewise with wv.
// One block = 16 codebook rows, 256 threads (thread = output channel c).
// ---------------------------------------------------------------------------
__global__ __launch_bounds__(256) void kv_kernel(
    const float* __restrict__ cb, const float* __restrict__ wk,
    const float* __restrict__ wv, float* __restrict__ kmat,
    float* __restrict__ vout) {
  __shared__ float cbs[16][CIN];
  const int t = threadIdx.x;
  const int k0 = blockIdx.x * 16;
#pragma unroll
  for (int i = 0; i < 16; ++i)
    cbs[i][t] = cb[(size_t)(k0 + i) * CIN + t];
  __syncthreads();
  float acck[16], accv[16];
#pragma unroll
  for (int r = 0; r < 16; ++r) { acck[r] = 0.f; accv[r] = 0.f; }
  const float* wkr = wk + (size_t)t * CIN;
  const float* wvr = wv + (size_t)t * CIN;
  for (int j = 0; j < CIN; ++j) {
    const float a = wkr[j];
    const float b = wvr[j];
#pragma unroll
    for (int r = 0; r < 16; ++r) {
      const float c = cbs[r][j];
      acck[r] = fmaf(c, a, acck[r]);
      accv[r] = fmaf(c, b, accv[r]);
    }
  }
#pragma unroll
  for (int r = 0; r < 16; ++r) {
    kmat[(size_t)(k0 + r) * CIN + t] = acck[r];
    vout[(size_t)(k0 + r) * CIN + t] = accv[r];
  }
}

// ---------------------------------------------------------------------------
// K2: q[p][d] = sum_c latent[n][c][h][w] * wq[d][c], p = n*1024 + h*32 + w.
// One block = 16 consecutive positions (same n), 256 threads (thread = d).
// ---------------------------------------------------------------------------
__global__ __launch_bounds__(256) void q_kernel(
    const float* __restrict__ latent, const float* __restrict__ wq,
    float* __restrict__ q) {
  __shared__ float lat[16][CIN];  // [hw offset][channel]
  const int t = threadIdx.x;
  const int p0 = blockIdx.x * 16;
  const int n = p0 >> 10, hw0 = p0 & 1023;
  const float* lbase = latent + (size_t)n * (CIN * 1024) + (size_t)t * 1024 + hw0;
#pragma unroll
  for (int i4 = 0; i4 < 4; ++i4) {
    float4 v4 = *(const float4*)(lbase + i4 * 4);
    lat[i4 * 4 + 0][t] = v4.x;
    lat[i4 * 4 + 1][t] = v4.y;
    lat[i4 * 4 + 2][t] = v4.z;
    lat[i4 * 4 + 3][t] = v4.w;
  }
  __syncthreads();
  float acc[16];
#pragma unroll
  for (int r = 0; r < 16; ++r) acc[r] = 0.f;
  const float* wqr = wq + (size_t)t * CIN;
  for (int j = 0; j < CIN; ++j) {
    const float w = wqr[j];
#pragma unroll
    for (int r = 0; r < 16; ++r) acc[r] = fmaf(lat[r][j], w, acc[r]);
  }
#pragma unroll
  for (int r = 0; r < 16; ++r)
    q[(size_t)(p0 + r) * CIN + t] = acc[r];
}

// ---------------------------------------------------------------------------
// K3: logit[m][k] = dot(q[m], kmat[k]) / 16.   M=16384, N=4096, K=256.
// 128x128 tile per 256-thread block; 8x8 micro-tile as 2x2 blocks of 4x4
// (keeps all LDS reads at 2-way aliasing = free on CDNA4).
// Per-element k-accumulation order identical to the 64x64 version (bit-exact
// logits -> identical argmax).
// ---------------------------------------------------------------------------
__global__ __launch_bounds__(256) void logit_kernel(
    const float* __restrict__ q, const float* __restrict__ kmat,
    float* __restrict__ logit) {
  __shared__ float As[16][132];  // [kk][row-in-tile], stride 132 (2-way banks)
  __shared__ float Bs[16][132];
  const int t = threadIdx.x;
  const int tx = t & 15, ty = t >> 4;
  const int n0 = blockIdx.x * 128;
  const int m0 = blockIdx.y * 128;

  float acc[8][8];
#pragma unroll
  for (int i = 0; i < 8; ++i)
#pragma unroll
    for (int j = 0; j < 8; ++j) acc[i][j] = 0.f;

  for (int k0 = 0; k0 < CIN; k0 += 16) {
#pragma unroll
    for (int i = 0; i < 2; ++i) {
      const int f = t + i * 256;
      const int row = f >> 2, c4 = f & 3;
      float4 a4 = *(const float4*)&q[(size_t)(m0 + row) * CIN + k0 + c4 * 4];
      float4 b4 = *(const float4*)&kmat[(size_t)(n0 + row) * CIN + k0 + c4 * 4];
      As[c4 * 4 + 0][row] = a4.x;
      As[c4 * 4 + 1][row] = a4.y;
      As[c4 * 4 + 2][row] = a4.z;
      As[c4 * 4 + 3][row] = a4.w;
      Bs[c4 * 4 + 0][row] = b4.x;
      Bs[c4 * 4 + 1][row] = b4.y;
      Bs[c4 * 4 + 2][row] = b4.z;
      Bs[c4 * 4 + 3][row] = b4.w;
    }
    __syncthreads();
#pragma unroll
    for (int kk = 0; kk < 16; ++kk) {
      float a[8], b[8];
      *(float4*)&a[0] = *(const float4*)&As[kk][ty * 4];
      *(float4*)&a[4] = *(const float4*)&As[kk][64 + ty * 4];
      *(float4*)&b[0] = *(const float4*)&Bs[kk][tx * 4];
      *(float4*)&b[4] = *(const float4*)&Bs[kk][64 + tx * 4];
#pragma unroll
      for (int i = 0; i < 8; ++i)
#pragma unroll
        for (int j = 0; j < 8; ++j) acc[i][j] = fmaf(a[i], b[j], acc[i][j]);
    }
    __syncthreads();
  }
  const float sc = 0.0625f;  // 1/sqrt(256)
#pragma unroll
  for (int ri = 0; ri < 2; ++ri)
#pragma unroll
    for (int i = 0; i < 4; ++i) {
      const int row = m0 + ri * 64 + ty * 4 + i;
      const int ai = ri * 4 + i;
#pragma unroll
      for (int ci = 0; ci < 2; ++ci) {
        float4 o = make_float4(acc[ai][ci * 4 + 0] * sc, acc[ai][ci * 4 + 1] * sc,
                               acc[ai][ci * 4 + 2] * sc, acc[ai][ci * 4 + 3] * sc);
        *(float4*)&logit[(size_t)row * KCB + n0 + ci * 64 + tx * 4] = o;
      }
    }
}

// ---------------------------------------------------------------------------
// K4: per-position argmax over 4096 logits; quantized[n,:,h,w] = v[idx]
// (soft_v cancels in (hard-soft)+soft to ~2ulp, so PV/softmax are skipped);
// idx output as float(idx & 255) (uint8 wrap).
// Ascending strict-> scan + min-index tie-break == np.argmax semantics.
// One block = 16 positions, 256 threads (16 lanes per row).
// ---------------------------------------------------------------------------
__global__ __launch_bounds__(256) void argmax_kernel(
    const float* __restrict__ logit, const float* __restrict__ vout,
    float* __restrict__ outq, float* __restrict__ outidx) {
  __shared__ int rowidx[16];
  const int t = threadIdx.x;
  const int p0 = blockIdx.x * 16;
  const int r = t >> 4, l16 = t & 15;
  const float* lrow = logit + (size_t)(p0 + r) * KCB;
  float m = -3.402823466e38f;
  int mi = 0;
  for (int kk = 0; kk < 64; ++kk) {
    const int k = l16 * 4 + kk * 64;
    const float4 x = *(const float4*)&lrow[k];
    if (x.x > m) { m = x.x; mi = k; }
    if (x.y > m) { m = x.y; mi = k + 1; }
    if (x.z > m) { m = x.z; mi = k + 2; }
    if (x.w > m) { m = x.w; mi = k + 3; }
  }
#pragma unroll
  for (int mask = 1; mask < 16; mask <<= 1) {
    const float om = __shfl_xor(m, mask, 64);
    const int oi = __shfl_xor(mi, mask, 64);
    if (om > m || (om == m && oi < mi)) { m = om; mi = oi; }
  }
  if (l16 == 0) rowidx[r] = mi;
  __syncthreads();

  const int n = p0 >> 10, hw0 = p0 & 1023;
  float res[16];
#pragma unroll
  for (int r2 = 0; r2 < 16; ++r2)
    res[r2] = vout[(size_t)rowidx[r2] * CIN + t];
  float* ob = outq + (size_t)n * (CIN * 1024) + (size_t)t * 1024 + hw0;
#pragma unroll
  for (int i4 = 0; i4 < 4; ++i4)
    *(float4*)&ob[i4 * 4] = make_float4(res[i4 * 4 + 0], res[i4 * 4 + 1],
                                        res[i4 * 4 + 2], res[i4 * 4 + 3]);
  if (t < 16) outidx[p0 + t] = (float)(rowidx[t] & 255);
}

// ---------------------------------------------------------------------------
extern "C" void kernel_launch(void* const* d_in, const int* in_sizes, int n_in,
                              void* d_out, int out_size, void* d_ws,
                              size_t ws_size, hipStream_t stream) {
  const float* latent = (const float*)d_in[0];
  // d_in[1] = temperature (unused in deterministic path)
  const float* codebook = (const float*)d_in[2];
  const float* wq = (const float*)d_in[3];
  const float* wk = (const float*)d_in[4];
  const float* wv = (const float*)d_in[5];

  float* out = (float*)d_out;
  float* outq = out + OFF_QUANT;
  float* outidx = out + OFF_IDX;
  float* outlogit = out + OFF_LOGIT;
  float* outv = out + OFF_V;

  float* q_ws = (float*)d_ws;                 // 16384*256 floats = 16 MB
  float* kmat_ws = q_ws + (size_t)NPOS * CIN; // 4096*256 floats = 4 MB

  kv_kernel<<<KCB / 16, 256, 0, stream>>>(codebook, wk, wv, kmat_ws, outv);
  q_kernel<<<NPOS / 16, 256, 0, stream>>>(latent, wq, q_ws);
  logit_kernel<<<dim3(KCB / 128, NPOS / 128), 256, 0, stream>>>(q_ws, kmat_ws,
                                                                outlogit);
  argmax_kernel<<<NPOS / 16, 256, 0, stream>>>(outlogit, outv, outq, outidx);
}

// Round 4
// 424.768 us; speedup vs baseline: 3.3249x; 1.3137x over previous
//
#include <hip/hip_runtime.h>
#include <math.h>
#include <float.h>

#define CIN 256
#define KCB 4096
#define NPOS 16384  // 16*32*32

// output offsets (in floats)
#define OFF_QUANT 0
#define OFF_IDX   4194304    // 16*256*32*32
#define OFF_LOGIT 4210688    // OFF_IDX + 16*32*32
#define OFF_V     71319552   // OFF_LOGIT + 16*32*32*4096

#define MARGIN 1e-4f  // ~300 sigma of the 3-term bf16-split logit error

typedef short bf16x8 __attribute__((ext_vector_type(8)));
typedef float f32x4 __attribute__((ext_vector_type(4)));

__device__ __forceinline__ unsigned short rne_bf16(float x) {
  const unsigned u = __float_as_uint(x);
  return (unsigned short)((u + 0x7FFFu + ((u >> 16) & 1u)) >> 16);
}
__device__ __forceinline__ float bf16_f(unsigned short h) {
  return __uint_as_float(((unsigned)h) << 16);
}

__device__ __forceinline__ void gload_lds16(const void* g, void* l) {
  __builtin_amdgcn_global_load_lds(
      (const __attribute__((address_space(1))) unsigned int*)g,
      (__attribute__((address_space(3))) unsigned int*)l, 16, 0, 0);
}

// ---------------------------------------------------------------------------
// K1: kmat/v = codebook @ {wk,wv}^T. Emits kmat as bf16 hi/lo split + v fp32.
// ---------------------------------------------------------------------------
__global__ __launch_bounds__(256) void kv_kernel(
    const float* __restrict__ cb, const float* __restrict__ wk,
    const float* __restrict__ wv, unsigned short* __restrict__ khi,
    unsigned short* __restrict__ klo, float* __restrict__ vout) {
  __shared__ float cbs[16][CIN];
  const int t = threadIdx.x;
  const int k0 = blockIdx.x * 16;
#pragma unroll
  for (int i = 0; i < 16; ++i)
    cbs[i][t] = cb[(size_t)(k0 + i) * CIN + t];
  __syncthreads();
  float acck[16], accv[16];
#pragma unroll
  for (int r = 0; r < 16; ++r) { acck[r] = 0.f; accv[r] = 0.f; }
  const float* wkr = wk + (size_t)t * CIN;
  const float* wvr = wv + (size_t)t * CIN;
  for (int j = 0; j < CIN; ++j) {
    const float a = wkr[j];
    const float b = wvr[j];
#pragma unroll
    for (int r = 0; r < 16; ++r) {
      const float c = cbs[r][j];
      acck[r] = fmaf(c, a, acck[r]);
      accv[r] = fmaf(c, b, accv[r]);
    }
  }
#pragma unroll
  for (int r = 0; r < 16; ++r) {
    const float xk = acck[r];
    const unsigned short h = rne_bf16(xk);
    khi[(size_t)(k0 + r) * CIN + t] = h;
    klo[(size_t)(k0 + r) * CIN + t] = rne_bf16(xk - bf16_f(h));
    vout[(size_t)(k0 + r) * CIN + t] = accv[r];
  }
}

// ---------------------------------------------------------------------------
// K2: q = latent x wq, emitted as bf16 hi/lo split.
// ---------------------------------------------------------------------------
__global__ __launch_bounds__(256) void q_kernel(
    const float* __restrict__ latent, const float* __restrict__ wq,
    unsigned short* __restrict__ qhi, unsigned short* __restrict__ qlo) {
  __shared__ float lat[16][CIN];
  const int t = threadIdx.x;
  const int p0 = blockIdx.x * 16;
  const int n = p0 >> 10, hw0 = p0 & 1023;
  const float* lbase = latent + (size_t)n * (CIN * 1024) + (size_t)t * 1024 + hw0;
#pragma unroll
  for (int i4 = 0; i4 < 4; ++i4) {
    float4 v4 = *(const float4*)(lbase + i4 * 4);
    lat[i4 * 4 + 0][t] = v4.x;
    lat[i4 * 4 + 1][t] = v4.y;
    lat[i4 * 4 + 2][t] = v4.z;
    lat[i4 * 4 + 3][t] = v4.w;
  }
  __syncthreads();
  float acc[16];
#pragma unroll
  for (int r = 0; r < 16; ++r) acc[r] = 0.f;
  const float* wqr = wq + (size_t)t * CIN;
  for (int j = 0; j < CIN; ++j) {
    const float w = wqr[j];
#pragma unroll
    for (int r = 0; r < 16; ++r) acc[r] = fmaf(lat[r][j], w, acc[r]);
  }
#pragma unroll
  for (int r = 0; r < 16; ++r) {
    const float x = acc[r];
    const unsigned short h = rne_bf16(x);
    qhi[(size_t)(p0 + r) * CIN + t] = h;
    qlo[(size_t)(p0 + r) * CIN + t] = rne_bf16(x - bf16_f(h));
  }
}

// ---------------------------------------------------------------------------
// K3: logit = (qh+ql)(kh+kl)^T / 16 via 3-term bf16 MFMA (hh + hl + lh).
// 128x128 tile, 4 waves of 64x64, BK=32, double-buffered global_load_lds.
// ---------------------------------------------------------------------------
__global__ __launch_bounds__(256) void logit_kernel(
    const unsigned short* __restrict__ qh, const unsigned short* __restrict__ ql,
    const unsigned short* __restrict__ kh, const unsigned short* __restrict__ kl,
    float* __restrict__ logit) {
  __shared__ unsigned short sAB[2][4][128 * 32];  // [buf][Ah,Al,Bh,Bl] 64 KB

  const int t = threadIdx.x;
  const int b = blockIdx.x;
  const int x = (b & 7) * 512 + (b >> 3);  // bijective XCD swizzle (4096 % 8 == 0)
  const int bn = x & 31, bm = x >> 5;
  const int n0 = bn * 128, m0 = bm * 128;

  const int lane = t & 63, w = t >> 6;
  const int wr = w >> 1, wc = w & 1;
  const int fr = lane & 15, fq = lane >> 4;

  const int srow = t >> 2;       // staging: 64 rows per issue
  const int skg = (t & 3) * 8;   // 8 bf16 (16 B) per lane

  f32x4 acc[4][4];
#pragma unroll
  for (int i = 0; i < 4; ++i)
#pragma unroll
    for (int j = 0; j < 4; ++j) acc[i][j] = (f32x4)(0.f);

  // prologue: stage step 0 into buf 0
#pragma unroll
  for (int h = 0; h < 2; ++h) {
    const int r = h * 64 + srow;
    gload_lds16(qh + (size_t)(m0 + r) * CIN + skg, &sAB[0][0][r * 32 + skg]);
    gload_lds16(ql + (size_t)(m0 + r) * CIN + skg, &sAB[0][1][r * 32 + skg]);
    gload_lds16(kh + (size_t)(n0 + r) * CIN + skg, &sAB[0][2][r * 32 + skg]);
    gload_lds16(kl + (size_t)(n0 + r) * CIN + skg, &sAB[0][3][r * 32 + skg]);
  }
  asm volatile("s_waitcnt vmcnt(0)" ::: "memory");
  __syncthreads();

  for (int s = 0; s < 8; ++s) {
    const int buf = s & 1;
    if (s < 7) {  // stage next tile into the other buffer
      const int k0 = (s + 1) * 32;
      const int nb = buf ^ 1;
#pragma unroll
      for (int h = 0; h < 2; ++h) {
        const int r = h * 64 + srow;
        gload_lds16(qh + (size_t)(m0 + r) * CIN + k0 + skg, &sAB[nb][0][r * 32 + skg]);
        gload_lds16(ql + (size_t)(m0 + r) * CIN + k0 + skg, &sAB[nb][1][r * 32 + skg]);
        gload_lds16(kh + (size_t)(n0 + r) * CIN + k0 + skg, &sAB[nb][2][r * 32 + skg]);
        gload_lds16(kl + (size_t)(n0 + r) * CIN + k0 + skg, &sAB[nb][3][r * 32 + skg]);
      }
    }
    bf16x8 ah[4], al[4], bh[4], bl[4];
#pragma unroll
    for (int mi = 0; mi < 4; ++mi) {
      const int off = (wr * 64 + mi * 16 + fr) * 32 + fq * 8;
      ah[mi] = *(const bf16x8*)&sAB[buf][0][off];
      al[mi] = *(const bf16x8*)&sAB[buf][1][off];
    }
#pragma unroll
    for (int ni = 0; ni < 4; ++ni) {
      const int off = (wc * 64 + ni * 16 + fr) * 32 + fq * 8;
      bh[ni] = *(const bf16x8*)&sAB[buf][2][off];
      bl[ni] = *(const bf16x8*)&sAB[buf][3][off];
    }
#pragma unroll
    for (int mi = 0; mi < 4; ++mi)
#pragma unroll
      for (int ni = 0; ni < 4; ++ni) {
        acc[mi][ni] = __builtin_amdgcn_mfma_f32_16x16x32_bf16(
            ah[mi], bh[ni], acc[mi][ni], 0, 0, 0);
        acc[mi][ni] = __builtin_amdgcn_mfma_f32_16x16x32_bf16(
            ah[mi], bl[ni], acc[mi][ni], 0, 0, 0);
        acc[mi][ni] = __builtin_amdgcn_mfma_f32_16x16x32_bf16(
            al[mi], bh[ni], acc[mi][ni], 0, 0, 0);
      }
    asm volatile("s_waitcnt vmcnt(0)" ::: "memory");
    __syncthreads();
  }

  // epilogue: scale by 1/16, write logit
  const float sc = 0.0625f;
#pragma unroll
  for (int mi = 0; mi < 4; ++mi)
#pragma unroll
    for (int i = 0; i < 4; ++i) {
      const int row = m0 + wr * 64 + mi * 16 + fq * 4 + i;
#pragma unroll
      for (int ni = 0; ni < 4; ++ni)
        logit[(size_t)row * KCB + n0 + wc * 64 + ni * 16 + fr] =
            acc[mi][ni][i] * sc;
    }
}

// ---------------------------------------------------------------------------
// K4: per-row argmax over MFMA logits with top-2 gap test. If gap <= MARGIN
// (~2% of rows), recompute candidate logits EXACTLY in fp32 from original
// inputs (np.argmax first-occurrence semantics). Then gather v[idx] ->
// quantized, idx as float(idx & 255).
// One block = 16 positions, 256 threads (16 lanes per row for the scan).
// ---------------------------------------------------------------------------
__global__ __launch_bounds__(256) void argmax_kernel(
    const float* __restrict__ logit, const float* __restrict__ vout,
    const float* __restrict__ latent, const float* __restrict__ wq,
    const float* __restrict__ cb, const float* __restrict__ wk,
    float* __restrict__ outq, float* __restrict__ outidx) {
  __shared__ int rowidx[16];
  __shared__ float rowm[16];
  __shared__ int rowflag[16];
  __shared__ float qex[256];
  __shared__ float red[256];
  __shared__ int clist[32];
  __shared__ int ccnt;
  __shared__ float s_bestv;
  __shared__ int s_bestj;

  const int t = threadIdx.x;
  const int p0 = blockIdx.x * 16;

  // ---- phase A: top-2 scan of the MFMA logit row ----
  {
    const int r = t >> 4, l16 = t & 15;
    const float* lrow = logit + (size_t)(p0 + r) * KCB;
    float m1 = -FLT_MAX, m2 = -FLT_MAX;
    int i1 = 0;
    for (int kk = 0; kk < 64; ++kk) {
      const int k = l16 * 4 + kk * 64;
      const float4 x = *(const float4*)&lrow[k];
      if (x.x > m1) { m2 = m1; m1 = x.x; i1 = k; } else if (x.x > m2) m2 = x.x;
      if (x.y > m1) { m2 = m1; m1 = x.y; i1 = k + 1; } else if (x.y > m2) m2 = x.y;
      if (x.z > m1) { m2 = m1; m1 = x.z; i1 = k + 2; } else if (x.z > m2) m2 = x.z;
      if (x.w > m1) { m2 = m1; m1 = x.w; i1 = k + 3; } else if (x.w > m2) m2 = x.w;
    }
#pragma unroll
    for (int mask = 1; mask < 16; mask <<= 1) {
      const float om1 = __shfl_xor(m1, mask, 64);
      const int oi1 = __shfl_xor(i1, mask, 64);
      const float om2 = __shfl_xor(m2, mask, 64);
      if (om1 > m1 || (om1 == m1 && oi1 < i1)) {
        m2 = fmaxf(m1, om2);
        m1 = om1;
        i1 = oi1;
      } else {
        m2 = fmaxf(m2, om1);
      }
    }
    if (l16 == 0) {
      rowidx[r] = i1;
      rowm[r] = m1;
      rowflag[r] = (m1 - m2 <= MARGIN) ? 1 : 0;
    }
  }
  __syncthreads();

  // ---- phase B: exact fp32 refinement for flagged rows (rare) ----
  for (int r2 = 0; r2 < 16; ++r2) {
    if (!rowflag[r2]) continue;  // uniform branch (shared)
    const int p = p0 + r2;
    const int n = p >> 10, hw = p & 1023;
    // exact q row: qex[d] = sum_c latent[n][c][hw] * wq[d][c]
    {
      const float* lb = latent + (size_t)n * (CIN * 1024) + hw;
      const float* wqr = wq + (size_t)t * CIN;
      float qd = 0.f;
      for (int c = 0; c < CIN; ++c) qd = fmaf(lb[(size_t)c * 1024], wqr[c], qd);
      qex[t] = qd;
    }
    if (t == 0) {
      ccnt = 0;
      s_bestv = -FLT_MAX;
      s_bestj = rowidx[r2];
    }
    __syncthreads();
    // collect candidates within margin of the MFMA max
    {
      const float thr = rowm[r2] - MARGIN;
      const float* lrow = logit + (size_t)p * KCB;
#pragma unroll
      for (int it = 0; it < 16; ++it) {
        const int j = t + it * 256;
        if (lrow[j] > thr) {
          const int pos = atomicAdd(&ccnt, 1);
          if (pos < 32) clist[pos] = j;
        }
      }
    }
    __syncthreads();
    const int nc = min(ccnt, 32);
    if (t == 0) {  // insertion sort ascending (tiny)
      for (int a = 1; a < nc; ++a) {
        const int key = clist[a];
        int bpos = a - 1;
        while (bpos >= 0 && clist[bpos] > key) {
          clist[bpos + 1] = clist[bpos];
          --bpos;
        }
        clist[bpos + 1] = key;
      }
    }
    __syncthreads();
    for (int ci = 0; ci < nc; ++ci) {
      const int j = clist[ci];
      // exact kmat row element d=t, then exact logit = dot(qex, krow)/16
      const float* cbr = cb + (size_t)j * CIN;
      const float* wkr = wk + (size_t)t * CIN;
      float kd = 0.f;
      for (int c = 0; c < CIN; ++c) kd = fmaf(cbr[c], wkr[c], kd);
      red[t] = qex[t] * kd;
      __syncthreads();
      for (int s = 128; s > 0; s >>= 1) {
        if (t < s) red[t] += red[t + s];
        __syncthreads();
      }
      if (t == 0) {
        const float val = red[0] * 0.0625f;
        if (val > s_bestv) { s_bestv = val; s_bestj = j; }  // ascending j: ties keep first
      }
      __syncthreads();
    }
    if (t == 0) rowidx[r2] = s_bestj;
    __syncthreads();
  }

  // ---- phase C: gather v[idx], write quantized + idx ----
  const int n = p0 >> 10, hw0 = p0 & 1023;
  float res[16];
#pragma unroll
  for (int r2 = 0; r2 < 16; ++r2)
    res[r2] = vout[(size_t)rowidx[r2] * CIN + t];
  float* ob = outq + (size_t)n * (CIN * 1024) + (size_t)t * 1024 + hw0;
#pragma unroll
  for (int i4 = 0; i4 < 4; ++i4)
    *(float4*)&ob[i4 * 4] = make_float4(res[i4 * 4 + 0], res[i4 * 4 + 1],
                                        res[i4 * 4 + 2], res[i4 * 4 + 3]);
  if (t < 16) outidx[p0 + t] = (float)(rowidx[t] & 255);
}

// ---------------------------------------------------------------------------
extern "C" void kernel_launch(void* const* d_in, const int* in_sizes, int n_in,
                              void* d_out, int out_size, void* d_ws,
                              size_t ws_size, hipStream_t stream) {
  const float* latent = (const float*)d_in[0];
  // d_in[1] = temperature (unused in deterministic path)
  const float* codebook = (const float*)d_in[2];
  const float* wq = (const float*)d_in[3];
  const float* wk = (const float*)d_in[4];
  const float* wv = (const float*)d_in[5];

  float* out = (float*)d_out;
  float* outq = out + OFF_QUANT;
  float* outidx = out + OFF_IDX;
  float* outlogit = out + OFF_LOGIT;
  float* outv = out + OFF_V;

  char* ws = (char*)d_ws;
  unsigned short* qh = (unsigned short*)ws;                                   // 8 MB
  unsigned short* ql = (unsigned short*)(ws + (size_t)NPOS * CIN * 2);        // 8 MB
  unsigned short* kh = (unsigned short*)(ws + (size_t)NPOS * CIN * 4);        // 2 MB
  unsigned short* kl =
      (unsigned short*)(ws + (size_t)NPOS * CIN * 4 + (size_t)KCB * CIN * 2); // 2 MB

  kv_kernel<<<KCB / 16, 256, 0, stream>>>(codebook, wk, wv, kh, kl, outv);
  q_kernel<<<NPOS / 16, 256, 0, stream>>>(latent, wq, qh, ql);
  logit_kernel<<<4096, 256, 0, stream>>>(qh, ql, kh, kl, outlogit);
  argmax_kernel<<<NPOS / 16, 256, 0, stream>>>(outlogit, outv, latent, wq,
                                               codebook, wk, outq, outidx);
}